// Round 9
// baseline (467.238 us; speedup 1.0000x reference)
//
#include <hip/hip_runtime.h>
#include <hip/hip_bf16.h>
#include <stdint.h>

#define NROWS 8192
#define KDIM  512
#define NC    11014
#define PADC  11136      // 87 * 128
#define CTILES 87        // column tiles of 128
#define RT    64         // row tiles of 128
#define NCHUNK (CTILES * 2)
#define NKT   16         // KDIM / BK

#define BM 128
#define BN 128
#define BK 32

#define SS    30.0f
#define COSM  0.8253356149096783f
#define SINM  0.5646424733950354f
#define THv  (-0.8253356149096783f)
#define MMv   0.33878548403702126f

typedef __attribute__((ext_vector_type(4))) float  f32x4;
typedef __attribute__((ext_vector_type(8))) __bf16 bf16x8;

// async global->LDS, 16B per lane; LDS dest is wave-uniform base + lane*16.
__device__ __forceinline__ void async16(const void* g, void* l) {
  __builtin_amdgcn_global_load_lds(
      (const __attribute__((address_space(1))) unsigned int*)(uintptr_t)g,
      (__attribute__((address_space(3))) unsigned int*)(uint32_t)(uintptr_t)l,
      16, 0, 0);
}

// streaming scalar store: sc0 sc1 nt (no-allocate policy; −12us proven R7->R8)
__device__ __forceinline__ void store_nt4(void* p, float v) {
  asm volatile("global_store_dword %0, %1, off sc0 sc1 nt"
               :: "v"(p), "v"(v) : "memory");
}

// ---------------- kernel 0: L2-normalize rows of x,w -> bf16 (wave per row) --
__global__ void norm_kernel(const float* __restrict__ x, const float* __restrict__ w,
                            __hip_bfloat16* __restrict__ xn, __hip_bfloat16* __restrict__ wn) {
  const int wid  = blockIdx.x * 4 + (threadIdx.x >> 6);
  const int lane = threadIdx.x & 63;
  const bool isx = (wid < NROWS);
  const int r = isx ? wid : (wid - NROWS);
  const bool pad = (!isx) && (r >= NC);
  const float* p = isx ? (x + (size_t)r * KDIM) : (w + (size_t)r * KDIM);
  f32x4 a = {0.f, 0.f, 0.f, 0.f}, b = {0.f, 0.f, 0.f, 0.f};
  if (!pad) {
    a = ((const f32x4*)p)[2 * lane];
    b = ((const f32x4*)p)[2 * lane + 1];
  }
  float ss = a[0]*a[0] + a[1]*a[1] + a[2]*a[2] + a[3]*a[3]
           + b[0]*b[0] + b[1]*b[1] + b[2]*b[2] + b[3]*b[3];
#pragma unroll
  for (int d = 1; d < 64; d <<= 1) ss += __shfl_xor(ss, d);
  const float scale = pad ? 0.f : (1.0f / fmaxf(sqrtf(ss), 1e-12f));
  __hip_bfloat16* o = isx ? (xn + (size_t)r * KDIM) : (wn + (size_t)r * KDIM);
  bf16x8 ov;
#pragma unroll
  for (int e = 0; e < 4; ++e) ov[e]     = (__bf16)(a[e] * scale);
#pragma unroll
  for (int e = 0; e < 4; ++e) ov[e + 4] = (__bf16)(b[e] * scale);
  *(bf16x8*)(o + lane * 8) = ov;
}

// ---------------- kernel 1: bf16 MFMA GEMM + ArcFace + partials --------------
// 3-buffer ring, 2-iters-ahead staging (vmcnt(8) steady state), direct nt
// stores in the epilogue.
__global__ __launch_bounds__(256, 3) void gemm_arc(
    const __hip_bfloat16* __restrict__ xn, const __hip_bfloat16* __restrict__ wn,
    const int* __restrict__ label, float* __restrict__ out,
    float2* __restrict__ parts) {
  // three 16KB buffers: buf b at sm + b*16384; A at +0, B at +8192 within buf.
  __shared__ __align__(16) char sm[49152];
  __shared__ int slbl[BM];

  const int tid  = threadIdx.x;
  const int w    = tid >> 6;
  const int lane = tid & 63;
  const int wr   = w >> 1, wc = w & 1;
  const int tc   = blockIdx.x;
  const int tr   = blockIdx.y;
  const int rowBase = tr * BM;
  const int colBase = tc * BN;

  if (tid < BM) slbl[tid] = label[rowBase + tid];

  f32x4 acc[4][4];
#pragma unroll
  for (int m = 0; m < 4; ++m)
#pragma unroll
    for (int n = 0; n < 4; ++n)
      acc[m][n] = (f32x4){0.f, 0.f, 0.f, 0.f};

  // staging: wave w covers rows [w*32, w*32+32): lane -> row w*32 + (lane>>2),
  // k-bytes (lane&3)*16; LDS linear [row][k], rows of 64B. 4 loads per STAGE.
  const __hip_bfloat16* ga = xn + (size_t)(rowBase + w * 32 + (lane >> 2)) * KDIM + (lane & 3) * 8;
  const __hip_bfloat16* gb = wn + (size_t)(colBase + w * 32 + (lane >> 2)) * KDIM + (lane & 3) * 8;

  // fragment offsets within a buffer: A row = wr*64+m*16+(lane&15), k-half = lane>>4
  const int aoff = (wr * 64 + (lane & 15)) * 64 + (lane >> 4) * 16;
  const int boff = 8192 + (wc * 64 + (lane & 15)) * 64 + (lane >> 4) * 16;

#define STAGE(kt, buf)                                                   \
  do {                                                                   \
    const __hip_bfloat16* pa = ga + (kt) * BK;                           \
    const __hip_bfloat16* pb = gb + (kt) * BK;                           \
    char* la = sm + (buf) * 16384 + w * 2048;                            \
    char* lb = sm + (buf) * 16384 + 8192 + w * 2048;                     \
    async16(pa,             la);                                         \
    async16(pa + 16 * KDIM, la + 1024);                                  \
    async16(pb,             lb);                                         \
    async16(pb + 16 * KDIM, lb + 1024);                                  \
  } while (0)

  STAGE(0, 0);
  STAGE(1, 1);
  STAGE(2, 2);           // 12 loads in flight

#pragma unroll
  for (int kt = 0; kt < NKT; ++kt) {
    // counted wait: tile kt done; tiles kt+1, kt+2 (up to 8 loads) in flight
    const int rem = NKT - 1 - kt;
    if (rem >= 2) {
      asm volatile("s_waitcnt vmcnt(8)" ::: "memory");
    } else if (rem == 1) {
      asm volatile("s_waitcnt vmcnt(4)" ::: "memory");
    } else {
      asm volatile("s_waitcnt vmcnt(0)" ::: "memory");
    }
    __builtin_amdgcn_s_barrier();      // buf[kt%3] ready for everyone

    const char* base = sm + (kt % 3) * 16384;
    bf16x8 af[4], bq[4];
#pragma unroll
    for (int m = 0; m < 4; ++m)
      af[m] = *(const bf16x8*)(base + aoff + m * 1024);
#pragma unroll
    for (int n = 0; n < 4; ++n)
      bq[n] = *(const bf16x8*)(base + boff + n * 1024);

    asm volatile("s_waitcnt lgkmcnt(0)" ::: "memory");  // my reads complete
    __builtin_amdgcn_sched_barrier(0);                  // pin reads above (rule #18)
    __builtin_amdgcn_s_barrier();                       // all waves done reading

    if (kt + 3 < NKT) STAGE(kt + 3, (kt + 3) % 3);      // overwrites buf kt%3: safe now

#pragma unroll
    for (int m = 0; m < 4; ++m)
#pragma unroll
      for (int n = 0; n < 4; ++n)
        acc[m][n] = __builtin_amdgcn_mfma_f32_16x16x32_bf16(af[m], bq[n], acc[m][n], 0, 0, 0);
  }
#undef STAGE

  // ---- epilogue: margin + partials + direct nt stores ----
  const int g4 = lane >> 4;
  const int c4 = lane & 15;
#pragma unroll
  for (int m = 0; m < 4; ++m) {
#pragma unroll
    for (int j = 0; j < 4; ++j) {
      const int lrow = wr * 64 + m * 16 + g4 * 4 + j;
      const int grow = rowBase + lrow;
      const int rl   = slbl[lrow];
      float v[4];
      float mx = -1e30f;
#pragma unroll
      for (int n = 0; n < 4; ++n) {
        const int gc = colBase + wc * 64 + n * 16 + c4;
        float c = acc[m][n][j];
        float logit = c * SS;
        if (gc == rl) {  // rare; execz-skipped
          float sine = sqrtf(fmaxf(0.f, 1.f - c * c));
          float phi  = c * COSM - sine * SINM;
          phi = (c > THv) ? phi : (c - MMv);
          logit = phi * SS;
        }
        if (gc < NC) {
          store_nt4(out + (size_t)grow * NC + gc, logit);
          v[n] = logit;
        } else {
          v[n] = -1e30f;
        }
        mx = fmaxf(mx, v[n]);
      }
#pragma unroll
      for (int d = 1; d < 16; d <<= 1) mx = fmaxf(mx, __shfl_xor(mx, d));
      float s = 0.f;
#pragma unroll
      for (int n = 0; n < 4; ++n)
        if (v[n] > -1e29f) s += __expf(v[n] - mx);
#pragma unroll
      for (int d = 1; d < 16; d <<= 1) s += __shfl_xor(s, d);
      if (c4 == 0) {
        parts[(size_t)(tc * 2 + wc) * NROWS + grow] = make_float2(mx, s);
      }
    }
  }
}

// ---------------- kernel 2: per-row logsumexp merge + NLL --------------------
// 256 blocks x 256 threads; 8 lanes per row (part = lane>>3), shuffle combine.
__global__ void merge_loss(const float2* __restrict__ parts, const float* __restrict__ out,
                           const int* __restrict__ label, float* __restrict__ rowloss) {
  const int tid  = threadIdx.x;
  const int lane = tid & 63;
  const int wv   = tid >> 6;
  const int part = lane >> 3;
  const int row  = blockIdx.x * 32 + wv * 8 + (lane & 7);
  float M = -1e30f;
  for (int c = part; c < NCHUNK; c += 8)
    M = fmaxf(M, parts[(size_t)c * NROWS + row].x);
  M = fmaxf(M, __shfl_xor(M, 8));
  M = fmaxf(M, __shfl_xor(M, 16));
  M = fmaxf(M, __shfl_xor(M, 32));
  float Ssum = 0.f;
  for (int c = part; c < NCHUNK; c += 8) {
    float2 pp = parts[(size_t)c * NROWS + row];
    if (pp.x > -1e29f) Ssum += pp.y * __expf(pp.x - M);
  }
  Ssum += __shfl_xor(Ssum, 8);
  Ssum += __shfl_xor(Ssum, 16);
  Ssum += __shfl_xor(Ssum, 32);
  if (part == 0) {
    const float lt = out[(size_t)row * NC + label[row]];
    rowloss[row] = M + logf(Ssum) - lt;
  }
}

// ---------------- kernel 3: deterministic mean ------------------------------
__global__ void final_loss(const float* __restrict__ rowloss, float* __restrict__ out_loss) {
  double s = 0.0;
  for (int i = threadIdx.x; i < NROWS; i += 256) s += (double)rowloss[i];
  __shared__ double sd[256];
  sd[threadIdx.x] = s;
  __syncthreads();
  for (int step = 128; step > 0; step >>= 1) {
    if (threadIdx.x < step) sd[threadIdx.x] += sd[threadIdx.x + step];
    __syncthreads();
  }
  if (threadIdx.x == 0) out_loss[0] = (float)(sd[0] / (double)NROWS);
}

extern "C" void kernel_launch(void* const* d_in, const int* in_sizes, int n_in,
                              void* d_out, int out_size, void* d_ws, size_t ws_size,
                              hipStream_t stream) {
  const float* x     = (const float*)d_in[0];
  const int*   label = (const int*)d_in[1];
  const float* w     = (const float*)d_in[2];
  float* out = (float*)d_out;

  char* ws = (char*)d_ws;
  __hip_bfloat16* xn = (__hip_bfloat16*)ws;                      //  8,388,608 B
  __hip_bfloat16* wn = (__hip_bfloat16*)(ws + 8388608);          // 11,403,264 B
  float2* parts      = (float2*)(ws + 19791872);                 // 11,403,264 B
  float*  rowloss    = (float*)(ws + 31195136);                  //     32,768 B

  norm_kernel<<<dim3((NROWS + PADC) / 4), dim3(256), 0, stream>>>(x, w, xn, wn);
  gemm_arc<<<dim3(CTILES, RT), dim3(256), 0, stream>>>(xn, wn, label, out, parts);
  merge_loss<<<dim3(256), dim3(256), 0, stream>>>(parts, out, label, rowloss);
  final_loss<<<dim3(1), dim3(256), 0, stream>>>(rowloss, out + (size_t)NROWS * NC);
}

// Round 10
// 210.103 us; speedup vs baseline: 2.2238x; 2.2238x over previous
//
#include <hip/hip_runtime.h>
#include <hip/hip_bf16.h>
#include <stdint.h>

#define NROWS 8192
#define KDIM  512
#define NC    11014
#define PADC  11136      // 87 * 128
#define CTILES 87        // column tiles of 128
#define RT    64         // row tiles of 128
#define NCHUNK (CTILES * 2)
#define NKT   16         // KDIM / BK

#define BM 128
#define BN 128
#define BK 32

#define SS    30.0f
#define COSM  0.8253356149096783f
#define SINM  0.5646424733950354f
#define THv  (-0.8253356149096783f)
#define MMv   0.33878548403702126f

typedef __attribute__((ext_vector_type(4))) float  f32x4;
typedef __attribute__((ext_vector_type(8))) __bf16 bf16x8;

// async global->LDS, 16B per lane; LDS dest is wave-uniform base + lane*16.
__device__ __forceinline__ void async16(const void* g, void* l) {
  __builtin_amdgcn_global_load_lds(
      (const __attribute__((address_space(1))) unsigned int*)(uintptr_t)g,
      (__attribute__((address_space(3))) unsigned int*)(uint32_t)(uintptr_t)l,
      16, 0, 0);
}

// ---------------- kernel 0: L2-normalize rows of x,w -> bf16 (wave per row) --
__global__ void norm_kernel(const float* __restrict__ x, const float* __restrict__ w,
                            __hip_bfloat16* __restrict__ xn, __hip_bfloat16* __restrict__ wn) {
  const int wid  = blockIdx.x * 4 + (threadIdx.x >> 6);
  const int lane = threadIdx.x & 63;
  const bool isx = (wid < NROWS);
  const int r = isx ? wid : (wid - NROWS);
  const bool pad = (!isx) && (r >= NC);
  const float* p = isx ? (x + (size_t)r * KDIM) : (w + (size_t)r * KDIM);
  f32x4 a = {0.f, 0.f, 0.f, 0.f}, b = {0.f, 0.f, 0.f, 0.f};
  if (!pad) {
    a = ((const f32x4*)p)[2 * lane];
    b = ((const f32x4*)p)[2 * lane + 1];
  }
  float ss = a[0]*a[0] + a[1]*a[1] + a[2]*a[2] + a[3]*a[3]
           + b[0]*b[0] + b[1]*b[1] + b[2]*b[2] + b[3]*b[3];
#pragma unroll
  for (int d = 1; d < 64; d <<= 1) ss += __shfl_xor(ss, d);
  const float scale = pad ? 0.f : (1.0f / fmaxf(sqrtf(ss), 1e-12f));
  __hip_bfloat16* o = isx ? (xn + (size_t)r * KDIM) : (wn + (size_t)r * KDIM);
  bf16x8 ov;
#pragma unroll
  for (int e = 0; e < 4; ++e) ov[e]     = (__bf16)(a[e] * scale);
#pragma unroll
  for (int e = 0; e < 4; ++e) ov[e + 4] = (__bf16)(b[e] * scale);
  *(bf16x8*)(o + lane * 8) = ov;
}

// ---------------- kernel 1: bf16 MFMA GEMM + ArcFace + partials --------------
// R6 structure + XCD-affine remap: xcd = bid&7 owns tr-band [xcd*8, xcd*8+8);
// within band, ct-major in groups of 8 tr -> B-tile and A-band stay L2-resident.
__global__ __launch_bounds__(256, 4) void gemm_arc(
    const __hip_bfloat16* __restrict__ xn, const __hip_bfloat16* __restrict__ wn,
    const int* __restrict__ label, float* __restrict__ out,
    float2* __restrict__ parts) {
  // two 16KB buffers: buf p at sm + p*16384; A at +0, B at +8192 within a buf.
  __shared__ __align__(16) char sm[32768];
  __shared__ int slbl[BM];

  const int tid  = threadIdx.x;
  const int w    = tid >> 6;
  const int lane = tid & 63;
  const int wr   = w >> 1, wc = w & 1;

  // XCD-affine decode (5568 = 8 XCD * 8 tr * 87 ct)
  const int bid = blockIdx.x;
  const int xcd = bid & 7;
  const int k   = bid >> 3;            // 0..695
  const int tr  = xcd * 8 + (k & 7);   // 8-row band per XCD
  const int tc  = k >> 3;              // ct-major: 8 consecutive blocks share B
  const int rowBase = tr * BM;
  const int colBase = tc * BN;

  if (tid < BM) slbl[tid] = label[rowBase + tid];

  f32x4 acc[4][4];
#pragma unroll
  for (int m = 0; m < 4; ++m)
#pragma unroll
    for (int n = 0; n < 4; ++n)
      acc[m][n] = (f32x4){0.f, 0.f, 0.f, 0.f};

  // staging: wave w covers rows [w*32, w*32+32): lane -> row w*32 + (lane>>2),
  // k-bytes (lane&3)*16; LDS linear [row][k], rows of 64B. 4 loads per STAGE.
  const __hip_bfloat16* ga = xn + (size_t)(rowBase + w * 32 + (lane >> 2)) * KDIM + (lane & 3) * 8;
  const __hip_bfloat16* gb = wn + (size_t)(colBase + w * 32 + (lane >> 2)) * KDIM + (lane & 3) * 8;

  // fragment offsets within a buffer: A row = wr*64+m*16+(lane&15), k-half = lane>>4
  const int aoff = (wr * 64 + (lane & 15)) * 64 + (lane >> 4) * 16;
  const int boff = 8192 + (wc * 64 + (lane & 15)) * 64 + (lane >> 4) * 16;

#define STAGE(kt, buf)                                                   \
  do {                                                                   \
    const __hip_bfloat16* pa = ga + (kt) * BK;                           \
    const __hip_bfloat16* pb = gb + (kt) * BK;                           \
    char* la = sm + (buf) * 16384 + w * 2048;                            \
    char* lb = sm + (buf) * 16384 + 8192 + w * 2048;                     \
    async16(pa,             la);                                         \
    async16(pa + 16 * KDIM, la + 1024);                                  \
    async16(pb,             lb);                                         \
    async16(pb + 16 * KDIM, lb + 1024);                                  \
  } while (0)

  STAGE(0, 0);
  STAGE(1, 1);           // 8 loads in flight

  int p = 0;
#pragma unroll
  for (int kt = 0; kt < NKT; ++kt) {
    // counted wait: this iter's 4 loads done, next iter's 4 remain in flight
    if (kt + 1 < NKT) {
      asm volatile("s_waitcnt vmcnt(4)" ::: "memory");
    } else {
      asm volatile("s_waitcnt vmcnt(0)" ::: "memory");
    }
    __builtin_amdgcn_s_barrier();      // buf[p] ready for everyone

    const char* base = sm + p * 16384;
    bf16x8 af[4], bq[4];
#pragma unroll
    for (int m = 0; m < 4; ++m)
      af[m] = *(const bf16x8*)(base + aoff + m * 1024);
#pragma unroll
    for (int n = 0; n < 4; ++n)
      bq[n] = *(const bf16x8*)(base + boff + n * 1024);

    asm volatile("s_waitcnt lgkmcnt(0)" ::: "memory");  // my reads complete
    __builtin_amdgcn_sched_barrier(0);                  // pin reads above (rule #18)
    __builtin_amdgcn_s_barrier();                       // all waves done reading

    if (kt + 2 < NKT) STAGE(kt + 2, p);                 // overwrite now safe

#pragma unroll
    for (int m = 0; m < 4; ++m)
#pragma unroll
      for (int n = 0; n < 4; ++n)
        acc[m][n] = __builtin_amdgcn_mfma_f32_16x16x32_bf16(af[m], bq[n], acc[m][n], 0, 0, 0);
    p ^= 1;
  }
#undef STAGE

  // ---- epilogue (R6 style): margin + partials + direct plain stores ----
  const int g4 = lane >> 4;
  const int c4 = lane & 15;
#pragma unroll
  for (int m = 0; m < 4; ++m) {
#pragma unroll
    for (int j = 0; j < 4; ++j) {
      const int lrow = wr * 64 + m * 16 + g4 * 4 + j;
      const int grow = rowBase + lrow;
      const int rl   = slbl[lrow];
      float v[4];
      float mx = -1e30f;
#pragma unroll
      for (int n = 0; n < 4; ++n) {
        const int gc = colBase + wc * 64 + n * 16 + c4;
        float c = acc[m][n][j];
        float logit = c * SS;
        if (gc == rl) {  // rare; execz-skipped
          float sine = sqrtf(fmaxf(0.f, 1.f - c * c));
          float phi  = c * COSM - sine * SINM;
          phi = (c > THv) ? phi : (c - MMv);
          logit = phi * SS;
        }
        if (gc < NC) {
          out[(size_t)grow * NC + gc] = logit;
          v[n] = logit;
        } else {
          v[n] = -1e30f;
        }
        mx = fmaxf(mx, v[n]);
      }
#pragma unroll
      for (int d = 1; d < 16; d <<= 1) mx = fmaxf(mx, __shfl_xor(mx, d));
      float s = 0.f;
#pragma unroll
      for (int n = 0; n < 4; ++n)
        if (v[n] > -1e29f) s += __expf(v[n] - mx);
#pragma unroll
      for (int d = 1; d < 16; d <<= 1) s += __shfl_xor(s, d);
      if (c4 == 0) {
        parts[(size_t)(tc * 2 + wc) * NROWS + grow] = make_float2(mx, s);
      }
    }
  }
}

// ---------------- kernel 2: per-row logsumexp merge + NLL --------------------
// 256 blocks x 256 threads; 8 lanes per row (part = lane>>3), shuffle combine.
__global__ void merge_loss(const float2* __restrict__ parts, const float* __restrict__ out,
                           const int* __restrict__ label, float* __restrict__ rowloss) {
  const int tid  = threadIdx.x;
  const int lane = tid & 63;
  const int wv   = tid >> 6;
  const int part = lane >> 3;
  const int row  = blockIdx.x * 32 + wv * 8 + (lane & 7);
  float M = -1e30f;
  for (int c = part; c < NCHUNK; c += 8)
    M = fmaxf(M, parts[(size_t)c * NROWS + row].x);
  M = fmaxf(M, __shfl_xor(M, 8));
  M = fmaxf(M, __shfl_xor(M, 16));
  M = fmaxf(M, __shfl_xor(M, 32));
  float Ssum = 0.f;
  for (int c = part; c < NCHUNK; c += 8) {
    float2 pp = parts[(size_t)c * NROWS + row];
    if (pp.x > -1e29f) Ssum += pp.y * __expf(pp.x - M);
  }
  Ssum += __shfl_xor(Ssum, 8);
  Ssum += __shfl_xor(Ssum, 16);
  Ssum += __shfl_xor(Ssum, 32);
  if (part == 0) {
    const float lt = out[(size_t)row * NC + label[row]];
    rowloss[row] = M + logf(Ssum) - lt;
  }
}

// ---------------- kernel 3: deterministic mean ------------------------------
__global__ void final_loss(const float* __restrict__ rowloss, float* __restrict__ out_loss) {
  double s = 0.0;
  for (int i = threadIdx.x; i < NROWS; i += 256) s += (double)rowloss[i];
  __shared__ double sd[256];
  sd[threadIdx.x] = s;
  __syncthreads();
  for (int step = 128; step > 0; step >>= 1) {
    if (threadIdx.x < step) sd[threadIdx.x] += sd[threadIdx.x + step];
    __syncthreads();
  }
  if (threadIdx.x == 0) out_loss[0] = (float)(sd[0] / (double)NROWS);
}

extern "C" void kernel_launch(void* const* d_in, const int* in_sizes, int n_in,
                              void* d_out, int out_size, void* d_ws, size_t ws_size,
                              hipStream_t stream) {
  const float* x     = (const float*)d_in[0];
  const int*   label = (const int*)d_in[1];
  const float* w     = (const float*)d_in[2];
  float* out = (float*)d_out;

  char* ws = (char*)d_ws;
  __hip_bfloat16* xn = (__hip_bfloat16*)ws;                      //  8,388,608 B
  __hip_bfloat16* wn = (__hip_bfloat16*)(ws + 8388608);          // 11,403,264 B
  float2* parts      = (float2*)(ws + 19791872);                 // 11,403,264 B
  float*  rowloss    = (float*)(ws + 31195136);                  //     32,768 B

  norm_kernel<<<dim3((NROWS + PADC) / 4), dim3(256), 0, stream>>>(x, w, xn, wn);
  gemm_arc<<<dim3(CTILES * RT), dim3(256), 0, stream>>>(xn, wn, label, out, parts);
  merge_loss<<<dim3(256), dim3(256), 0, stream>>>(parts, out, label, rowloss);
  final_loss<<<dim3(1), dim3(256), 0, stream>>>(rowloss, out + (size_t)NROWS * NC);
}